// Round 2
// baseline (238.251 us; speedup 1.0000x reference)
//
#include <hip/hip_runtime.h>
#include <stdint.h>

// Depthwise causal conv1d, channel-last. x:(B,L,D) f32, w:(K,1,D), b:(D), y:(B,L,D).
// y[n,l,d] = sum_k w[k,d]*x[n,l+k-3,d] + b[d], zero-padded left.
//
// R6: wave-private ring pipeline, ZERO barriers.
// R5 post-mortem: 64-row shared ring had a 67-row live window (32 compute + 3
// halo + 32 prefetch) -> prefetch clobbered wave 0's halo slots, cross-wave
// race. Fix: each wave owns a private 64-row L-segment and a private 16-row
// LDS ring (16 KB). Per 8-row chunk: issue next chunk's 8 global_load_lds
// (slots (l+8)&15), s_waitcnt vmcnt(16) (drains THIS chunk's loads, leaves
// prev stores + next loads in flight), ds_read 8 rows, FMA, 8 nontemporal
// stores. Halo is carried in registers across chunks (sliding window of the
// SAME wave), so compute slots (lc..lc+7)&15 and prefetch slots (lc+8..+15)&15
// are always disjoint. Producer == consumer wave => no s_barrier anywhere;
// stores are never drained inside the loop.

#define CB 4
#define CL 4096
#define CD 2048
#define STRIP 256                // floats per channel strip (1 KB per row-strip)
#define SF4 (STRIP / 4)          // 64 float4 per row-strip
#define HALO 3
#define RW 16                    // ring rows per wave (16 KB)
#define CROWS 8                  // rows per wave-chunk
#define WROWS 64                 // rows per wave
#define NCH (WROWS / CROWS)      // 8 chunks per wave
#define BROWS (WROWS * 4)        // 256 rows per block (4 waves)
#define NSTRIP (CD / STRIP)      // 8
#define NSEG (CL / BROWS)        // 16

typedef float nfloat4 __attribute__((ext_vector_type(4)));

__global__ __launch_bounds__(256) void short_conv_kernel(
    const float* __restrict__ x,
    const float* __restrict__ w,
    const float* __restrict__ bias,
    float* __restrict__ y)
{
    __shared__ __align__(16) float lds[4 * RW * STRIP];   // 64 KB -> 2 blocks/CU

    const int tid  = threadIdx.x;
    const int lane = tid & 63;
    const int wv   = tid >> 6;

    const int bid   = blockIdx.x;
    const int strip = bid & (NSTRIP - 1);
    const int seg   = (bid >> 3) & (NSEG - 1);
    const int b     = bid >> 7;

    const int lw0 = seg * BROWS + wv * WROWS;  // first output row of this wave
    const int c0  = strip * STRIP;

    const float* xs = x + (size_t)b * CL * CD + c0;   // strip base, row stride CD
    float*       ys = y + (size_t)b * CL * CD + c0;

    float* ldsw = lds + wv * RW * STRIP;              // wave-private 16-row ring

    // ---- Initial stage: rows lw0-3 .. lw0+7 into ring slot (l & 15). ----
#pragma unroll
    for (int r = 0; r < CROWS + HALO; ++r) {
        const int l = lw0 - HALO + r;                 // wave-uniform
        if (l >= 0) {
            const float* gsrc = xs + (size_t)l * CD + lane * 4;
            float* ldst = &ldsw[(l & (RW - 1)) * STRIP + lane * 4];
            __builtin_amdgcn_global_load_lds(
                (const __attribute__((address_space(1))) uint32_t*)gsrc,
                (__attribute__((address_space(3))) uint32_t*)ldst,
                16, 0, 0);
        }
    }

    // Per-lane weights/bias for columns c0 + lane*4 .. +3 (L2-resident, tiny).
    const float4 w0 = *(const float4*)(w + 0 * CD + c0 + lane * 4);
    const float4 w1 = *(const float4*)(w + 1 * CD + c0 + lane * 4);
    const float4 w2 = *(const float4*)(w + 2 * CD + c0 + lane * 4);
    const float4 w3 = *(const float4*)(w + 3 * CD + c0 + lane * 4);
    const float4 bv = *(const float4*)(bias + c0 + lane * 4);

    // Drain initial stage (wave-local; no barrier needed -- ring is private).
    asm volatile("s_waitcnt vmcnt(0)" ::: "memory");
    __builtin_amdgcn_sched_barrier(0);

    const float4* lrow = (const float4*)ldsw + lane;   // ring row stride SF4

    // Halo into registers BEFORE chunk-0's prefetch can clobber slots 13..15.
    float4 xm3, xm2, xm1;
    if (lw0 == 0) {
        xm3 = xm2 = xm1 = make_float4(0.f, 0.f, 0.f, 0.f);
    } else {
        xm3 = lrow[((lw0 - 3) & (RW - 1)) * SF4];
        xm2 = lrow[((lw0 - 2) & (RW - 1)) * SF4];
        xm1 = lrow[((lw0 - 1) & (RW - 1)) * SF4];
    }
    asm volatile("s_waitcnt lgkmcnt(0)" ::: "memory");
    __builtin_amdgcn_sched_barrier(0);

    for (int c = 0; c < NCH; ++c) {
        const int lc = lw0 + c * CROWS;

        if (c + 1 < NCH) {
            // ---- Prefetch next chunk: rows lc+8..lc+15 -> slots (l&15),
            // disjoint from this chunk's compute slots. ----
#pragma unroll
            for (int r = 0; r < CROWS; ++r) {
                const int l = lc + CROWS + r;          // wave-uniform
                const float* gsrc = xs + (size_t)l * CD + lane * 4;
                float* ldst = &ldsw[(l & (RW - 1)) * STRIP + lane * 4];
                __builtin_amdgcn_global_load_lds(
                    (const __attribute__((address_space(1))) uint32_t*)gsrc,
                    (__attribute__((address_space(3))) uint32_t*)ldst,
                    16, 0, 0);
            }
            __builtin_amdgcn_sched_barrier(0);
            // FIFO: [loads(c):8][stores(c-1):<=8][loads(c+1):8] -> vmcnt(16)
            // completes loads(c); stores + next loads stay in flight.
            asm volatile("s_waitcnt vmcnt(16)" ::: "memory");
        } else {
            // Last chunk: only [loads(c):8][stores(c-1):<=8] outstanding.
            asm volatile("s_waitcnt vmcnt(8)" ::: "memory");
        }
        __builtin_amdgcn_sched_barrier(0);

        // ---- Compute 8 rows with register sliding window. ----
#pragma unroll
        for (int t = 0; t < CROWS; ++t) {
            const int l = lc + t;
            const float4 a0 = lrow[(l & (RW - 1)) * SF4];

            nfloat4 r;
            r.x = fmaf(w0.x, xm3.x, fmaf(w1.x, xm2.x, fmaf(w2.x, xm1.x, fmaf(w3.x, a0.x, bv.x))));
            r.y = fmaf(w0.y, xm3.y, fmaf(w1.y, xm2.y, fmaf(w2.y, xm1.y, fmaf(w3.y, a0.y, bv.y))));
            r.z = fmaf(w0.z, xm3.z, fmaf(w1.z, xm2.z, fmaf(w2.z, xm1.z, fmaf(w3.z, a0.z, bv.z))));
            r.w = fmaf(w0.w, xm3.w, fmaf(w1.w, xm2.w, fmaf(w2.w, xm1.w, fmaf(w3.w, a0.w, bv.w))));

            __builtin_nontemporal_store(r, (nfloat4*)(ys + (size_t)l * CD + lane * 4));

            xm3 = xm2;
            xm2 = xm1;
            xm1 = a0;
        }
    }
}

extern "C" void kernel_launch(void* const* d_in, const int* in_sizes, int n_in,
                              void* d_out, int out_size, void* d_ws, size_t ws_size,
                              hipStream_t stream) {
    const float* x = (const float*)d_in[0];
    const float* w = (const float*)d_in[1];
    const float* b = (const float*)d_in[2];
    float* y = (float*)d_out;

    const int grid = CB * NSTRIP * NSEG;   // 4 * 8 * 16 = 512 blocks, 2/CU exact
    short_conv_kernel<<<grid, 256, 0, stream>>>(x, w, b, y);
}

// Round 5
// 236.133 us; speedup vs baseline: 1.0090x; 1.0090x over previous
//
#include <hip/hip_runtime.h>
#include <stdint.h>

// Depthwise causal conv1d, channel-last. x:(B,L,D) f32, w:(K,1,D), b:(D), y:(B,L,D).
// y[n,l,d] = sum_k w[k,d]*x[n,l+k-3,d] + b[d], zero-padded left.
//
// R9 == R8 == R7 resubmitted (two consecutive broker/container infra failures;
// kernel audited for OOB/fault vectors -- none; it never reached hardware).
// NO LDS. Register-ring streaming, 16 waves/CU.
// R6 post-mortem: 64 KB LDS ring -> 2 blocks/CU (8 waves), VALUBusy 4.5%,
// occupancy 17.9%, 3.3 TB/s effective -- latency-bound, and every byte paid an
// HBM->LDS->VGPR round-trip. The m13 copy kernel (6.3 TB/s, same 50/50 r/w mix)
// uses no LDS; this op is a copy + 4-tap FIR, and the FIR window fits in regs.
//
// Each wave owns 32 rows x 256-float strip. 8-slot float4 register ring
// (indices (t+k)&7 are compile-time after unroll -> VGPRs, no scratch).
// Per row: issue load(l+5) into the slot freed 3 rows ago, a0 = ring[t&7]
// (compiler inserts the precise counted vmcnt), 16 FMA vs register-carried
// xm3/xm2/xm1 halo window, nontemporal store. ~5 loads in flight/wave x
// 16 waves/CU >> Little's-law requirement. Zero barriers, zero LDS.

#define CB 4
#define CL 4096
#define CD 2048
#define STRIP 256               // floats per channel strip (1 KB per row per wave)
#define HALO 3
#define WROWS 32                // rows per wave
#define NSTRIP (CD / STRIP)     // 8
#define NSEG (CL / (WROWS * 4)) // 32 segments (4 waves/block)

typedef float nfloat4 __attribute__((ext_vector_type(4)));

__global__ __launch_bounds__(256, 4) void short_conv_kernel(
    const float* __restrict__ x,
    const float* __restrict__ w,
    const float* __restrict__ bias,
    float* __restrict__ y)
{
    const int tid  = threadIdx.x;
    const int lane = tid & 63;
    const int wv   = tid >> 6;

    const int bid   = blockIdx.x;
    const int strip = bid & (NSTRIP - 1);
    const int seg   = (bid >> 3) & (NSEG - 1);
    const int b     = bid >> 8;

    const int r0 = (seg * 4 + wv) * WROWS;     // first output row of this wave
    const int c0 = strip * STRIP;

    // Per-lane column base: this lane owns floats c0+lane*4 .. +3 of every row.
    const float* xs = x + (size_t)b * CL * CD + c0 + lane * 4;
    float*       ys = y + (size_t)b * CL * CD + c0 + lane * 4;

    // Per-lane weights/bias (L2-resident, tiny).
    const float4 w0 = *(const float4*)(w + 0 * CD + c0 + lane * 4);
    const float4 w1 = *(const float4*)(w + 1 * CD + c0 + lane * 4);
    const float4 w2 = *(const float4*)(w + 2 * CD + c0 + lane * 4);
    const float4 w3 = *(const float4*)(w + 3 * CD + c0 + lane * 4);
    const float4 bv = *(const float4*)(bias + c0 + lane * 4);

    // ---- Register ring: slot(l) = (l - r0) & 7. Prologue loads rows
    // r0-3..r0+4 into slots 5,6,7,0,1,2,3,4 (halo skipped for r0==0). ----
    float4 buf[8];
    float4 xm3, xm2, xm1;

    if (r0 > 0) {
        buf[5] = *(const float4*)(xs + (size_t)(r0 - 3) * CD);
        buf[6] = *(const float4*)(xs + (size_t)(r0 - 2) * CD);
        buf[7] = *(const float4*)(xs + (size_t)(r0 - 1) * CD);
    } else {
        buf[5] = buf[6] = buf[7] = make_float4(0.f, 0.f, 0.f, 0.f);
    }
#pragma unroll
    for (int r = 0; r < 5; ++r) {
        buf[r] = *(const float4*)(xs + (size_t)(r0 + r) * CD);
    }
    xm3 = buf[5];
    xm2 = buf[6];
    xm1 = buf[7];

    // ---- Main loop: 4 x 8 rows. Slot indices depend only on t (static). ----
    for (int c = 0; c < 4; ++c) {
#pragma unroll
        for (int t = 0; t < 8; ++t) {
            const int l = r0 + c * 8 + t;

            // Prefetch row l+5 into the slot freed at iteration l-3.
            // Clamp keeps the issue count wave-uniform (vmcnt arithmetic) and
            // in-bounds at the tail; clamped junk rows are never consumed.
            const int lp = (l + 5 < CL) ? (l + 5) : (CL - 1);
            buf[(t + 5) & 7] = *(const float4*)(xs + (size_t)lp * CD);

            const float4 a0 = buf[t & 7];

            nfloat4 r;
            r.x = fmaf(w0.x, xm3.x, fmaf(w1.x, xm2.x, fmaf(w2.x, xm1.x, fmaf(w3.x, a0.x, bv.x))));
            r.y = fmaf(w0.y, xm3.y, fmaf(w1.y, xm2.y, fmaf(w2.y, xm1.y, fmaf(w3.y, a0.y, bv.y))));
            r.z = fmaf(w0.z, xm3.z, fmaf(w1.z, xm2.z, fmaf(w2.z, xm1.z, fmaf(w3.z, a0.z, bv.z))));
            r.w = fmaf(w0.w, xm3.w, fmaf(w1.w, xm2.w, fmaf(w2.w, xm1.w, fmaf(w3.w, a0.w, bv.w))));

            __builtin_nontemporal_store(r, (nfloat4*)(ys + (size_t)l * CD));

            xm3 = xm2;
            xm2 = xm1;
            xm1 = a0;
        }
    }
}

extern "C" void kernel_launch(void* const* d_in, const int* in_sizes, int n_in,
                              void* d_out, int out_size, void* d_ws, size_t ws_size,
                              hipStream_t stream) {
    const float* x = (const float*)d_in[0];
    const float* w = (const float*)d_in[1];
    const float* b = (const float*)d_in[2];
    float* y = (float*)d_out;

    const int grid = CB * NSTRIP * NSEG;   // 4 * 8 * 32 = 1024 blocks, 4/CU
    short_conv_kernel<<<grid, 256, 0, stream>>>(x, w, b, y);
}